// Round 5
// baseline (157.084 us; speedup 1.0000x reference)
//
#include <hip/hip_runtime.h>
#include <stdint.h>

#define BB 8
#define NN 4096
#define MM 32
#define KK 72
#define DD 78
#define PAD 76            // LDS row stride (floats): 76*4=304 B, 16B-aligned

static constexpr float EPSF = 1e-12f;

__device__ inline bool getmask(const void* masks, int flag, int i) {
  if (flag) return ((const unsigned char*)masks)[i] != 0;
  return ((const int*)masks)[i] != 0;
}

// ---------- init: zero matchmask + maxima, detect mask dtype ----------------
__global__ __launch_bounds__(256) void k_init(
    unsigned* __restrict__ mmask, unsigned* __restrict__ maxima,
    int* __restrict__ flag, const unsigned char* __restrict__ masks_raw) {
  int idx = blockIdx.x * 256 + threadIdx.x;     // over B*N
  if (idx < BB * NN) mmask[idx] = 0u;
  if (idx < BB * 3) maxima[idx] = 0u;
  if (blockIdx.x == 0 && threadIdx.x < 64) {
    // int32 masks: bytes at i%4!=0 are always 0. bool/u8: ~80% are 1.
    int i = threadIdx.x * 4;
    bool nz = false;
#pragma unroll
    for (int j = 1; j < 4; ++j)
      if (masks_raw[i + j] != 0) nz = true;
    unsigned long long bal = __ballot(nz);
    if (threadIdx.x == 0) *flag = (bal != 0ull) ? 1 : 0;
  }
}

// ---------- pass A: one thread per (n,m) pair --------------------------------
// grid: BB*512 blocks; block = 8 n  x 32 m  (256 threads)
__global__ __launch_bounds__(256) void k_pairs(
    const float* __restrict__ preds, const float* __restrict__ tgts,
    const int* __restrict__ imgw_p,
    float* __restrict__ dist, float* __restrict__ xyd, float* __restrict__ thd,
    float* __restrict__ iou, float* __restrict__ cls,
    unsigned* __restrict__ maxima) {
  __shared__ __align__(16) float t_xs[MM][PAD];
  __shared__ __align__(16) float px_s[8][PAD];
  __shared__ float t_cx[MM], t_cy[MM], t_th[MM], t_len[MM], v30[MM];
  __shared__ float redv[4][3];

  const int b = blockIdx.x >> 9;
  const int n0 = (blockIdx.x & 511) << 3;
  const int tid = threadIdx.x;
  const float imgw = (float)(*imgw_p);

  // stage targets for this batch
  for (int idx = tid; idx < MM * DD; idx += 256) {
    int m = idx / DD, j = idx - m * DD;
    float v = tgts[((size_t)b * MM + m) * DD + j];
    if (j >= 6) t_xs[m][j - 6] = v;
    else if (j == 2) t_cx[m] = v;
    else if (j == 3) t_cy[m] = v;
    else if (j == 4) t_th[m] = v;
  }
  // stage the 8 pred x-rows
  for (int idx = tid; idx < 8 * KK; idx += 256) {
    int ni = idx / KK, k = idx - ni * KK;
    px_s[ni][k] = preds[((size_t)b * NN + (n0 + ni)) * DD + 6 + k];
  }
  // focal-cost class diffs for this block's 8 rows (2 labels each)
  if (tid < 16) {
    int ni = tid >> 1, c = tid & 1;
    float lg = preds[((size_t)b * NN + (n0 + ni)) * DD + c];
    float pp = 1.0f / (1.0f + expf(-lg));
    float neg = -logf(1.0f - pp + EPSF) * 0.75f * (pp * pp);
    float pos = -logf(pp + EPSF) * 0.25f * ((1.0f - pp) * (1.0f - pp));
    cls[((size_t)b * NN + (n0 + ni)) * 2 + c] = pos - neg;
  }
  __syncthreads();
  if (tid < MM) {
    int V = 0;
    for (int k = 0; k < KK; ++k) {
      float t = t_xs[tid][k];
      if (t >= 0.0f && t < imgw) V++;
    }
    t_len[tid] = (float)(V > 0 ? V : 1);
    v30[tid] = 30.0f * (float)V;           // 2*IOU_LEN * valid-count (exact)
  }
  __syncthreads();

  const int m = tid >> 3;        // 0..31
  const int ni = tid & 7;        // 0..7
  const int n = n0 + ni;

  // masked sum of |t-p| over k (sequential k order -> bitwise == reference)
  float sad = 0.f;
  const float4* trow = reinterpret_cast<const float4*>(&t_xs[m][0]);
  const float4* prow = reinterpret_cast<const float4*>(&px_s[ni][0]);
#pragma unroll
  for (int q = 0; q < KK / 4; ++q) {
    float4 t4 = trow[q];
    float4 p4 = prow[q];
#pragma unroll
    for (int e = 0; e < 4; ++e) {
      float t = (e == 0) ? t4.x : (e == 1) ? t4.y : (e == 2) ? t4.z : t4.w;
      float p = (e == 0) ? p4.x : (e == 1) ? p4.y : (e == 2) ? p4.z : p4.w;
      bool valid = (t >= 0.0f) && (t < imgw);
      float d = fabsf(t - p);                 // == max(t,p)-min(t,p) bitwise
      sad += valid ? d : 0.0f;
    }
  }

  const float* prowg = preds + ((size_t)b * NN + n) * DD;
  const float pcx = prowg[2], pcy = prowg[3], pth = prowg[4];
  float dval = sad / t_len[m];
  float dx = pcx - t_cx[m], dy = pcy - t_cy[m];
  float xyv = sqrtf(dx * dx + dy * dy);
  float thv = fabsf(pth - t_th[m]);
  // sum(ovr) = 30V - sad ; sum(union) = 30V + sad  (algebraic identity)
  float iv = (v30[m] - sad) / ((v30[m] + sad) + 1e-9f);

  size_t o = ((size_t)(b * MM + m)) * NN + n;
  dist[o] = dval;
  xyd[o] = xyv;
  thd[o] = thv;
  iou[o] = iv;

  // block max of (dval, xyv, thv) -> 3 atomicMax per block (nonneg floats)
  float md = dval, mxy = xyv, mth = thv;
  for (int off = 32; off; off >>= 1) {
    md = fmaxf(md, __shfl_down(md, off));
    mxy = fmaxf(mxy, __shfl_down(mxy, off));
    mth = fmaxf(mth, __shfl_down(mth, off));
  }
  if ((tid & 63) == 0) {
    int w = tid >> 6;
    redv[w][0] = md; redv[w][1] = mxy; redv[w][2] = mth;
  }
  __syncthreads();
  if (tid == 0) {
    float a0 = fmaxf(fmaxf(redv[0][0], redv[1][0]), fmaxf(redv[2][0], redv[3][0]));
    float a1 = fmaxf(fmaxf(redv[0][1], redv[1][1]), fmaxf(redv[2][1], redv[3][1]));
    float a2 = fmaxf(fmaxf(redv[0][2], redv[1][2]), fmaxf(redv[2][2], redv[3][2]));
    atomicMax(&maxima[b * 3 + 0], __float_as_uint(a0));
    atomicMax(&maxima[b * 3 + 1], __float_as_uint(a1));
    atomicMax(&maxima[b * 3 + 2], __float_as_uint(a2));
  }
}

// ---------- pass C: fused cost + per-(b,m) top-4 selection ------------------
// one block (1024 threads = 16 waves) per (b,m); thread t owns n = 4t..4t+3
__global__ __launch_bounds__(1024) void k_assign(
    const float* __restrict__ dist, const float* __restrict__ xyd,
    const float* __restrict__ thd, const float* __restrict__ iou,
    const float* __restrict__ cls, const float* __restrict__ tgts,
    const unsigned* __restrict__ maxima, const void* __restrict__ masks,
    const int* __restrict__ flag, unsigned* __restrict__ mmask) {
  const int b = blockIdx.x >> 5;
  const int m = blockIdx.x & 31;
  if (!getmask(masks, *flag, b * MM + m)) return;   // block-uniform exit

  const int tid = threadIdx.x;
  const int n0 = tid << 2;
  const size_t o = ((size_t)(b * MM + m)) * NN + n0;

  const float maxd = fmaxf(__uint_as_float(maxima[b * 3 + 0]), 1e-6f);
  const float maxxy = fmaxf(__uint_as_float(maxima[b * 3 + 1]), 1e-6f);
  const float maxth = fmaxf(__uint_as_float(maxima[b * 3 + 2]), 1e-6f);
  const int label = (int)tgts[((size_t)b * MM + m) * DD + 1];

  float4 d4 = *reinterpret_cast<const float4*>(dist + o);
  float4 x4 = *reinterpret_cast<const float4*>(xyd + o);
  float4 t4 = *reinterpret_cast<const float4*>(thd + o);
  float4 i4 = *reinterpret_cast<const float4*>(iou + o);
  const float4* cbase = reinterpret_cast<const float4*>(cls + ((size_t)b * NN + n0) * 2);
  float4 c0 = cbase[0], c1 = cbase[1];

  float de[4] = {d4.x, d4.y, d4.z, d4.w};
  float xe[4] = {x4.x, x4.y, x4.z, x4.w};
  float te[4] = {t4.x, t4.y, t4.z, t4.w};
  float ie[4] = {i4.x, i4.y, i4.z, i4.w};
  float clv[4] = {label ? c0.y : c0.x, label ? c0.w : c0.z,
                  label ? c1.y : c1.x, label ? c1.w : c1.z};

  float cc[4]; int ci[4]; float vv[4];
#pragma unroll
  for (int e = 0; e < 4; ++e) {
    float ds = (1.0f - de[e] / maxd) + 0.01f;
    float xs = (1.0f - xe[e] / maxxy) + 0.01f;
    float ts = (1.0f - te[e] / maxth) + 0.01f;
    float r = (ds * xs) * ts;
    cc[e] = -(r * r) * 3.0f + clv[e] * 1.0f;
    ci[e] = n0 + e;
    vv[e] = fmaxf(ie[e], 0.0f);
  }

  __shared__ float ls_c[64];  __shared__ int ls_ci[64];
  __shared__ float ls_v[64];  __shared__ int ls_vi[64];

  const int wid = tid >> 6, lane = tid & 63;
  unsigned usedC = 0, usedV = 0;
  float wcv[4]; int wci[4]; float wvv[4]; int wvi[4];

#pragma unroll
  for (int r = 0; r < 4; ++r) {
    // ---- cost: extract wave min by (c asc, idx asc) ----
    float bv = 3e38f; int bi = 0x7fffffff; int be = -1;
#pragma unroll
    for (int e = 0; e < 4; ++e)
      if (!((usedC >> e) & 1) && (cc[e] < bv || (cc[e] == bv && ci[e] < bi))) {
        bv = cc[e]; bi = ci[e]; be = e;
      }
    float v = bv; int i = bi;
#pragma unroll
    for (int off = 32; off; off >>= 1) {
      float ov = __shfl_xor(v, off); int oi = __shfl_xor(i, off);
      if (ov < v || (ov == v && oi < i)) { v = ov; i = oi; }
    }
    if (be >= 0 && i == bi) usedC |= 1u << be;   // unique n -> unique winner
    wcv[r] = v; wci[r] = i;

    // ---- iou: extract wave max by (v desc, idx asc) ----
    float bw = -1.0f; int bj = 0x7fffffff; int bf = -1;
#pragma unroll
    for (int e = 0; e < 4; ++e)
      if (!((usedV >> e) & 1) && (vv[e] > bw || (vv[e] == bw && ci[e] < bj))) {
        bw = vv[e]; bj = ci[e]; bf = e;
      }
    float w = bw; int j = bj;
#pragma unroll
    for (int off = 32; off; off >>= 1) {
      float ow = __shfl_xor(w, off); int oj = __shfl_xor(j, off);
      if (ow > w || (ow == w && oj < j)) { w = ow; j = oj; }
    }
    if (bf >= 0 && j == bj) usedV |= 1u << bf;
    wvv[r] = w; wvi[r] = j;
  }

  if (lane == 0) {
#pragma unroll
    for (int r = 0; r < 4; ++r) {
      ls_c[wid * 4 + r] = wcv[r]; ls_ci[wid * 4 + r] = wci[r];
      ls_v[wid * 4 + r] = wvv[r]; ls_vi[wid * 4 + r] = wvi[r];
    }
  }
  __syncthreads();

  if (tid < 64) {
    float c = ls_c[tid]; int i = ls_ci[tid];
    float w = ls_v[tid]; int j = ls_vi[tid];
    int gidx[4]; float gsum = 0.0f;
#pragma unroll
    for (int r = 0; r < 4; ++r) {
      float v = c; int vi = i;
#pragma unroll
      for (int off = 32; off; off >>= 1) {
        float ov = __shfl_xor(v, off); int oi = __shfl_xor(vi, off);
        if (ov < v || (ov == v && oi < vi)) { v = ov; vi = oi; }
      }
      if (i == vi) c = 3e38f;                    // consume winner
      gidx[r] = vi;

      float u = w; int ui = j;
#pragma unroll
      for (int off = 32; off; off >>= 1) {
        float ou = __shfl_xor(u, off); int oi = __shfl_xor(ui, off);
        if (ou > u || (ou == u && oi < ui)) { u = ou; ui = oi; }
      }
      if (j == ui) w = -1.0f;
      gsum += u;
    }
    if (tid == 0) {
      int k = (int)gsum;                         // trunc == floor (gsum >= 0)
      if (k < 1) k = 1;
      if (k > 4) k = 4;
      for (int s = 0; s < k; ++s)
        atomicOr(&mmask[(size_t)b * NN + gidx[s]], 1u << m);
    }
  }
}

// ---------- pass D: conflict resolution + outputs ---------------------------
__global__ __launch_bounds__(256) void k_final(
    const unsigned* __restrict__ mmask, const float* __restrict__ dist,
    const float* __restrict__ xyd, const float* __restrict__ thd,
    const float* __restrict__ cls, const float* __restrict__ tgts,
    const unsigned* __restrict__ maxima, int* __restrict__ out) {
  int idx = blockIdx.x * 256 + threadIdx.x;   // over B*N
  if (idx >= BB * NN) return;
  int b = idx >> 12;
  int n = idx & (NN - 1);
  unsigned mm = mmask[idx];
  int a, t;
  int pc = __popc(mm);
  if (pc == 0) {
    a = 0; t = -1;
  } else if (pc == 1) {
    a = 1; t = __ffs(mm) - 1;
  } else {
    a = 1;
    float maxd = fmaxf(__uint_as_float(maxima[b * 3 + 0]), 1e-6f);
    float maxxy = fmaxf(__uint_as_float(maxima[b * 3 + 1]), 1e-6f);
    float maxth = fmaxf(__uint_as_float(maxima[b * 3 + 2]), 1e-6f);
    float best = 3e38f;
    int bi = -1;
    unsigned r0 = mm;
    while (r0) {
      int m = __ffs(r0) - 1;
      r0 &= r0 - 1;
      size_t o = ((size_t)(b * MM + m)) * NN + n;
      int label = (int)tgts[((size_t)b * MM + m) * DD + 1];
      float ds = (1.0f - dist[o] / maxd) + 0.01f;
      float xs = (1.0f - xyd[o] / maxxy) + 0.01f;
      float ts = (1.0f - thd[o] / maxth) + 0.01f;
      float r = (ds * xs) * ts;
      float c = -(r * r) * 3.0f + cls[((size_t)b * NN + n) * 2 + label] * 1.0f;
      if (c < best) { best = c; bi = m; }   // strict < -> lowest m wins ties
    }
    t = bi;
  }
  out[idx] = a;
  out[BB * NN + idx] = t;
}

extern "C" void kernel_launch(void* const* d_in, const int* in_sizes, int n_in,
                              void* d_out, int out_size, void* d_ws, size_t ws_size,
                              hipStream_t stream) {
  const float* preds = (const float*)d_in[0];
  const float* tgts = (const float*)d_in[1];
  const void* masks = d_in[2];
  const int* imgw = (const int*)d_in[3];

  char* ws = (char*)d_ws;
  const size_t MAT = (size_t)BB * MM * NN * sizeof(float);   // 4 MiB
  float* dist = (float*)(ws + 0 * MAT);
  float* xyd  = (float*)(ws + 1 * MAT);
  float* thd  = (float*)(ws + 2 * MAT);
  float* iou  = (float*)(ws + 3 * MAT);
  float* cls  = (float*)(ws + 4 * MAT);                       // B*N*2 floats
  char* p = ws + 4 * MAT + (size_t)BB * NN * 2 * sizeof(float);
  unsigned* maxima = (unsigned*)p;                            // B*3
  p += 256;
  unsigned* mmask = (unsigned*)p;                             // B*N
  p += (size_t)BB * NN * sizeof(unsigned);
  int* flag = (int*)p;

  k_init<<<dim3((BB * NN + 255) / 256), dim3(256), 0, stream>>>(
      mmask, maxima, flag, (const unsigned char*)masks);
  k_pairs<<<dim3(BB * 512), dim3(256), 0, stream>>>(
      preds, tgts, imgw, dist, xyd, thd, iou, cls, maxima);
  k_assign<<<dim3(BB * MM), dim3(1024), 0, stream>>>(
      dist, xyd, thd, iou, cls, tgts, maxima, masks, flag, mmask);
  k_final<<<dim3((BB * NN + 255) / 256), dim3(256), 0, stream>>>(
      mmask, dist, xyd, thd, cls, tgts, maxima, (int*)d_out);
}

// Round 6
// 64.504 us; speedup vs baseline: 2.4353x; 2.4353x over previous
//
#include <hip/hip_runtime.h>
#include <stdint.h>

#define BB 8
#define NN 4096
#define MM 32
#define KK 72
#define DD 78
#define PAD 76            // LDS row stride (floats): 76*4=304 B, 16B-aligned

static constexpr float EPSF = 1e-12f;

__device__ inline bool getmask(const void* masks, int flag, int i) {
  if (flag) return ((const unsigned char*)masks)[i] != 0;
  return ((const int*)masks)[i] != 0;
}

// ---------- init: zero matchmask, detect mask dtype -------------------------
__global__ __launch_bounds__(256) void k_init(
    unsigned* __restrict__ mmask, int* __restrict__ flag,
    const unsigned char* __restrict__ masks_raw) {
  int idx = blockIdx.x * 256 + threadIdx.x;     // over B*N
  if (idx < BB * NN) mmask[idx] = 0u;
  if (blockIdx.x == 0 && threadIdx.x < 64) {
    // int32 masks: bytes at i%4!=0 are always 0. bool/u8: ~80% are 1.
    int i = threadIdx.x * 4;
    bool nz = false;
#pragma unroll
    for (int j = 1; j < 4; ++j)
      if (masks_raw[i + j] != 0) nz = true;
    unsigned long long bal = __ballot(nz);
    if (threadIdx.x == 0) *flag = (bal != 0ull) ? 1 : 0;
  }
}

// ---------- pass A: one thread per (n,m) pair --------------------------------
// grid: BB*512 blocks; block = 8 n  x 32 m  (256 threads)
__global__ __launch_bounds__(256) void k_pairs(
    const float* __restrict__ preds, const float* __restrict__ tgts,
    const int* __restrict__ imgw_p,
    float* __restrict__ dist, float* __restrict__ xyd, float* __restrict__ thd,
    float* __restrict__ iou, float* __restrict__ cls,
    float* __restrict__ part) {
  __shared__ __align__(16) float t_xs[MM][PAD];
  __shared__ __align__(16) float px_s[8][PAD];
  __shared__ float t_cx[MM], t_cy[MM], t_th[MM], t_len[MM], v30[MM];
  __shared__ float redv[4][3];

  const int b = blockIdx.x >> 9;
  const int n0 = (blockIdx.x & 511) << 3;
  const int tid = threadIdx.x;
  const float imgw = (float)(*imgw_p);

  // stage targets for this batch
  for (int idx = tid; idx < MM * DD; idx += 256) {
    int m = idx / DD, j = idx - m * DD;
    float v = tgts[((size_t)b * MM + m) * DD + j];
    if (j >= 6) t_xs[m][j - 6] = v;
    else if (j == 2) t_cx[m] = v;
    else if (j == 3) t_cy[m] = v;
    else if (j == 4) t_th[m] = v;
  }
  // stage the 8 pred x-rows
  for (int idx = tid; idx < 8 * KK; idx += 256) {
    int ni = idx / KK, k = idx - ni * KK;
    px_s[ni][k] = preds[((size_t)b * NN + (n0 + ni)) * DD + 6 + k];
  }
  // focal-cost class diffs for this block's 8 rows (2 labels each)
  if (tid < 16) {
    int ni = tid >> 1, c = tid & 1;
    float lg = preds[((size_t)b * NN + (n0 + ni)) * DD + c];
    float pp = 1.0f / (1.0f + expf(-lg));
    float neg = -logf(1.0f - pp + EPSF) * 0.75f * (pp * pp);
    float pos = -logf(pp + EPSF) * 0.25f * ((1.0f - pp) * (1.0f - pp));
    cls[((size_t)b * NN + (n0 + ni)) * 2 + c] = pos - neg;
  }
  __syncthreads();
  if (tid < MM) {
    int V = 0;
    for (int k = 0; k < KK; ++k) {
      float t = t_xs[tid][k];
      if (t >= 0.0f && t < imgw) V++;
    }
    t_len[tid] = (float)(V > 0 ? V : 1);
    v30[tid] = 30.0f * (float)V;           // 2*IOU_LEN * valid-count (exact)
  }
  __syncthreads();

  const int m = tid >> 3;        // 0..31
  const int ni = tid & 7;        // 0..7
  const int n = n0 + ni;

  // masked sum of |t-p| over k (sequential k order -> bitwise == reference)
  float sad = 0.f;
  const float4* trow = reinterpret_cast<const float4*>(&t_xs[m][0]);
  const float4* prow = reinterpret_cast<const float4*>(&px_s[ni][0]);
#pragma unroll
  for (int q = 0; q < KK / 4; ++q) {
    float4 t4 = trow[q];
    float4 p4 = prow[q];
#pragma unroll
    for (int e = 0; e < 4; ++e) {
      float t = (e == 0) ? t4.x : (e == 1) ? t4.y : (e == 2) ? t4.z : t4.w;
      float p = (e == 0) ? p4.x : (e == 1) ? p4.y : (e == 2) ? p4.z : p4.w;
      bool valid = (t >= 0.0f) && (t < imgw);
      float d = fabsf(t - p);                 // == max(t,p)-min(t,p) bitwise
      sad += valid ? d : 0.0f;
    }
  }

  const float* prowg = preds + ((size_t)b * NN + n) * DD;
  const float pcx = prowg[2], pcy = prowg[3], pth = prowg[4];
  float dval = sad / t_len[m];
  float dx = pcx - t_cx[m], dy = pcy - t_cy[m];
  float xyv = sqrtf(dx * dx + dy * dy);
  float thv = fabsf(pth - t_th[m]);
  // sum(ovr) = 30V - sad ; sum(union) = 30V + sad  (algebraic identity)
  float iv = (v30[m] - sad) / ((v30[m] + sad) + 1e-9f);

  size_t o = ((size_t)(b * MM + m)) * NN + n;
  dist[o] = dval;
  xyd[o] = xyv;
  thd[o] = thv;
  iou[o] = iv;

  // block max of (dval, xyv, thv) -> plain store to part[block][3] (NO atomics:
  // 12K same-line atomicMax serialized ~98us in round 5)
  float md = dval, mxy = xyv, mth = thv;
  for (int off = 32; off; off >>= 1) {
    md = fmaxf(md, __shfl_down(md, off));
    mxy = fmaxf(mxy, __shfl_down(mxy, off));
    mth = fmaxf(mth, __shfl_down(mth, off));
  }
  if ((tid & 63) == 0) {
    int w = tid >> 6;
    redv[w][0] = md; redv[w][1] = mxy; redv[w][2] = mth;
  }
  __syncthreads();
  if (tid == 0) {
    float a0 = fmaxf(fmaxf(redv[0][0], redv[1][0]), fmaxf(redv[2][0], redv[3][0]));
    float a1 = fmaxf(fmaxf(redv[0][1], redv[1][1]), fmaxf(redv[2][1], redv[3][1]));
    float a2 = fmaxf(fmaxf(redv[0][2], redv[1][2]), fmaxf(redv[2][2], redv[3][2]));
    part[(size_t)blockIdx.x * 3 + 0] = a0;
    part[(size_t)blockIdx.x * 3 + 1] = a1;
    part[(size_t)blockIdx.x * 3 + 2] = a2;
  }
}

// ---------- reduce per-block partial maxima -> maxima[b][3] -----------------
__global__ __launch_bounds__(64) void k_red(const float* __restrict__ part,
                                            float* __restrict__ maxima) {
  int b = blockIdx.x / 3, j = blockIdx.x - b * 3;
  int lane = threadIdx.x;
  float v = 0.f;
  for (int t = lane; t < 512; t += 64)
    v = fmaxf(v, part[((size_t)b * 512 + t) * 3 + j]);
  for (int off = 32; off; off >>= 1) v = fmaxf(v, __shfl_down(v, off));
  if (lane == 0) maxima[b * 3 + j] = v;
}

// ---------- pass C: fused cost + per-(b,m) top-4 selection ------------------
// one block (1024 threads = 16 waves) per (b,m); thread t owns n = 4t..4t+3
__global__ __launch_bounds__(1024) void k_assign(
    const float* __restrict__ dist, const float* __restrict__ xyd,
    const float* __restrict__ thd, const float* __restrict__ iou,
    const float* __restrict__ cls, const float* __restrict__ tgts,
    const float* __restrict__ maxima, const void* __restrict__ masks,
    const int* __restrict__ flag, unsigned* __restrict__ mmask) {
  const int b = blockIdx.x >> 5;
  const int m = blockIdx.x & 31;
  if (!getmask(masks, *flag, b * MM + m)) return;   // block-uniform exit

  const int tid = threadIdx.x;
  const int n0 = tid << 2;
  const size_t o = ((size_t)(b * MM + m)) * NN + n0;

  const float maxd = fmaxf(maxima[b * 3 + 0], 1e-6f);
  const float maxxy = fmaxf(maxima[b * 3 + 1], 1e-6f);
  const float maxth = fmaxf(maxima[b * 3 + 2], 1e-6f);
  const int label = (int)tgts[((size_t)b * MM + m) * DD + 1];

  float4 d4 = *reinterpret_cast<const float4*>(dist + o);
  float4 x4 = *reinterpret_cast<const float4*>(xyd + o);
  float4 t4 = *reinterpret_cast<const float4*>(thd + o);
  float4 i4 = *reinterpret_cast<const float4*>(iou + o);
  const float4* cbase = reinterpret_cast<const float4*>(cls + ((size_t)b * NN + n0) * 2);
  float4 c0 = cbase[0], c1 = cbase[1];

  float de[4] = {d4.x, d4.y, d4.z, d4.w};
  float xe[4] = {x4.x, x4.y, x4.z, x4.w};
  float te[4] = {t4.x, t4.y, t4.z, t4.w};
  float ie[4] = {i4.x, i4.y, i4.z, i4.w};
  float clv[4] = {label ? c0.y : c0.x, label ? c0.w : c0.z,
                  label ? c1.y : c1.x, label ? c1.w : c1.z};

  float cc[4]; int ci[4]; float vv[4];
#pragma unroll
  for (int e = 0; e < 4; ++e) {
    float ds = (1.0f - de[e] / maxd) + 0.01f;
    float xs = (1.0f - xe[e] / maxxy) + 0.01f;
    float ts = (1.0f - te[e] / maxth) + 0.01f;
    float r = (ds * xs) * ts;
    cc[e] = -(r * r) * 3.0f + clv[e] * 1.0f;
    ci[e] = n0 + e;
    vv[e] = fmaxf(ie[e], 0.0f);
  }

  __shared__ float ls_c[64];  __shared__ int ls_ci[64];
  __shared__ float ls_v[64];  __shared__ int ls_vi[64];

  const int wid = tid >> 6, lane = tid & 63;
  unsigned usedC = 0, usedV = 0;
  float wcv[4]; int wci[4]; float wvv[4]; int wvi[4];

#pragma unroll
  for (int r = 0; r < 4; ++r) {
    // ---- cost: extract wave min by (c asc, idx asc) ----
    float bv = 3e38f; int bi = 0x7fffffff; int be = -1;
#pragma unroll
    for (int e = 0; e < 4; ++e)
      if (!((usedC >> e) & 1) && (cc[e] < bv || (cc[e] == bv && ci[e] < bi))) {
        bv = cc[e]; bi = ci[e]; be = e;
      }
    float v = bv; int i = bi;
#pragma unroll
    for (int off = 32; off; off >>= 1) {
      float ov = __shfl_xor(v, off); int oi = __shfl_xor(i, off);
      if (ov < v || (ov == v && oi < i)) { v = ov; i = oi; }
    }
    if (be >= 0 && i == bi) usedC |= 1u << be;   // unique n -> unique winner
    wcv[r] = v; wci[r] = i;

    // ---- iou: extract wave max by (v desc, idx asc) ----
    float bw = -1.0f; int bj = 0x7fffffff; int bf = -1;
#pragma unroll
    for (int e = 0; e < 4; ++e)
      if (!((usedV >> e) & 1) && (vv[e] > bw || (vv[e] == bw && ci[e] < bj))) {
        bw = vv[e]; bj = ci[e]; bf = e;
      }
    float w = bw; int j = bj;
#pragma unroll
    for (int off = 32; off; off >>= 1) {
      float ow = __shfl_xor(w, off); int oj = __shfl_xor(j, off);
      if (ow > w || (ow == w && oj < j)) { w = ow; j = oj; }
    }
    if (bf >= 0 && j == bj) usedV |= 1u << bf;
    wvv[r] = w; wvi[r] = j;
  }

  if (lane == 0) {
#pragma unroll
    for (int r = 0; r < 4; ++r) {
      ls_c[wid * 4 + r] = wcv[r]; ls_ci[wid * 4 + r] = wci[r];
      ls_v[wid * 4 + r] = wvv[r]; ls_vi[wid * 4 + r] = wvi[r];
    }
  }
  __syncthreads();

  if (tid < 64) {
    float c = ls_c[tid]; int i = ls_ci[tid];
    float w = ls_v[tid]; int j = ls_vi[tid];
    int gidx[4]; float gsum = 0.0f;
#pragma unroll
    for (int r = 0; r < 4; ++r) {
      float v = c; int vi = i;
#pragma unroll
      for (int off = 32; off; off >>= 1) {
        float ov = __shfl_xor(v, off); int oi = __shfl_xor(vi, off);
        if (ov < v || (ov == v && oi < vi)) { v = ov; vi = oi; }
      }
      if (i == vi) c = 3e38f;                    // consume winner
      gidx[r] = vi;

      float u = w; int ui = j;
#pragma unroll
      for (int off = 32; off; off >>= 1) {
        float ou = __shfl_xor(u, off); int oi = __shfl_xor(ui, off);
        if (ou > u || (ou == u && oi < ui)) { u = ou; ui = oi; }
      }
      if (j == ui) w = -1.0f;
      gsum += u;
    }
    if (tid == 0) {
      int k = (int)gsum;                         // trunc == floor (gsum >= 0)
      if (k < 1) k = 1;
      if (k > 4) k = 4;
      for (int s = 0; s < k; ++s)
        atomicOr(&mmask[(size_t)b * NN + gidx[s]], 1u << m);
    }
  }
}

// ---------- pass D: conflict resolution + outputs ---------------------------
__global__ __launch_bounds__(256) void k_final(
    const unsigned* __restrict__ mmask, const float* __restrict__ dist,
    const float* __restrict__ xyd, const float* __restrict__ thd,
    const float* __restrict__ cls, const float* __restrict__ tgts,
    const float* __restrict__ maxima, int* __restrict__ out) {
  int idx = blockIdx.x * 256 + threadIdx.x;   // over B*N
  if (idx >= BB * NN) return;
  int b = idx >> 12;
  int n = idx & (NN - 1);
  unsigned mm = mmask[idx];
  int a, t;
  int pc = __popc(mm);
  if (pc == 0) {
    a = 0; t = -1;
  } else if (pc == 1) {
    a = 1; t = __ffs(mm) - 1;
  } else {
    a = 1;
    float maxd = fmaxf(maxima[b * 3 + 0], 1e-6f);
    float maxxy = fmaxf(maxima[b * 3 + 1], 1e-6f);
    float maxth = fmaxf(maxima[b * 3 + 2], 1e-6f);
    float best = 3e38f;
    int bi = -1;
    unsigned r0 = mm;
    while (r0) {
      int m = __ffs(r0) - 1;
      r0 &= r0 - 1;
      size_t o = ((size_t)(b * MM + m)) * NN + n;
      int label = (int)tgts[((size_t)b * MM + m) * DD + 1];
      float ds = (1.0f - dist[o] / maxd) + 0.01f;
      float xs = (1.0f - xyd[o] / maxxy) + 0.01f;
      float ts = (1.0f - thd[o] / maxth) + 0.01f;
      float r = (ds * xs) * ts;
      float c = -(r * r) * 3.0f + cls[((size_t)b * NN + n) * 2 + label] * 1.0f;
      if (c < best) { best = c; bi = m; }   // strict < -> lowest m wins ties
    }
    t = bi;
  }
  out[idx] = a;
  out[BB * NN + idx] = t;
}

extern "C" void kernel_launch(void* const* d_in, const int* in_sizes, int n_in,
                              void* d_out, int out_size, void* d_ws, size_t ws_size,
                              hipStream_t stream) {
  const float* preds = (const float*)d_in[0];
  const float* tgts = (const float*)d_in[1];
  const void* masks = d_in[2];
  const int* imgw = (const int*)d_in[3];

  char* ws = (char*)d_ws;
  const size_t MAT = (size_t)BB * MM * NN * sizeof(float);   // 4 MiB
  float* dist = (float*)(ws + 0 * MAT);
  float* xyd  = (float*)(ws + 1 * MAT);
  float* thd  = (float*)(ws + 2 * MAT);
  float* iou  = (float*)(ws + 3 * MAT);
  float* cls  = (float*)(ws + 4 * MAT);                       // B*N*2 floats
  char* p = ws + 4 * MAT + (size_t)BB * NN * 2 * sizeof(float);
  float* part = (float*)p;                                    // B*512*3 floats
  p += (size_t)BB * 512 * 3 * sizeof(float);
  float* maxima = (float*)p;                                  // B*3
  p += 256;
  unsigned* mmask = (unsigned*)p;                             // B*N
  p += (size_t)BB * NN * sizeof(unsigned);
  int* flag = (int*)p;

  k_init<<<dim3((BB * NN + 255) / 256), dim3(256), 0, stream>>>(
      mmask, flag, (const unsigned char*)masks);
  k_pairs<<<dim3(BB * 512), dim3(256), 0, stream>>>(
      preds, tgts, imgw, dist, xyd, thd, iou, cls, part);
  k_red<<<dim3(BB * 3), dim3(64), 0, stream>>>(part, maxima);
  k_assign<<<dim3(BB * MM), dim3(1024), 0, stream>>>(
      dist, xyd, thd, iou, cls, tgts, maxima, masks, flag, mmask);
  k_final<<<dim3((BB * NN + 255) / 256), dim3(256), 0, stream>>>(
      mmask, dist, xyd, thd, cls, tgts, maxima, (int*)d_out);
}

// Round 7
// 54.962 us; speedup vs baseline: 2.8581x; 1.1736x over previous
//
#include <hip/hip_runtime.h>
#include <stdint.h>

#define BB 8
#define NN 4096
#define MM 32
#define KK 72
#define DD 78
#define PAD 76            // LDS row stride (floats): 76*4=304 B, 16B-aligned

static constexpr float EPSF = 1e-12f;

__device__ inline bool getmask(const void* masks, int flag, int i) {
  if (flag) return ((const unsigned char*)masks)[i] != 0;
  return ((const int*)masks)[i] != 0;
}

// ---------- pass A: 1024 blocks = 8 b x 128 n-chunks(32 n); 256 thr = 32 m x 8 ni;
// each thread computes 4 pairs (m, n0+ni+8j). Also: mmask zero, flag, cls table.
__global__ __launch_bounds__(256) void k_pairs(
    const float* __restrict__ preds, const float* __restrict__ tgts,
    const int* __restrict__ imgw_p, const unsigned char* __restrict__ masks_raw,
    float4* __restrict__ pair4, float* __restrict__ cls,
    float* __restrict__ part, unsigned* __restrict__ mmask,
    int* __restrict__ flag) {
  __shared__ __align__(16) float t_xs[MM][PAD];
  __shared__ __align__(16) float am_s[MM][PAD];   // valid ? 1.0 : 0.0
  __shared__ __align__(16) float px_s[32][PAD];
  __shared__ float pc_s[32][4];                   // cx, cy, th
  __shared__ float t_cx[MM], t_cy[MM], t_th[MM], t_len[MM], v30[MM];
  __shared__ float redv[4][3];

  const int b = blockIdx.x >> 7;
  const int n0 = (blockIdx.x & 127) << 5;         // 32 n per block
  const int tid = threadIdx.x;
  const float imgw = (float)(*imgw_p);

  // zero this block's mmask slice (1024 blocks x 32 = B*N)
  if (tid < 32) mmask[blockIdx.x * 32 + tid] = 0u;
  // mask dtype detect (block 0, wave 0): int32 masks have zero bytes at i%4!=0
  if (blockIdx.x == 0 && tid < 64) {
    int i = tid * 4;
    bool nz = false;
#pragma unroll
    for (int j = 1; j < 4; ++j)
      if (masks_raw[i + j] != 0) nz = true;
    unsigned long long bal = __ballot(nz);
    if (tid == 0) *flag = (bal != 0ull) ? 1 : 0;
  }

  // stage targets for this batch
  for (int idx = tid; idx < MM * DD; idx += 256) {
    int m = idx / DD, j = idx - m * DD;
    float v = tgts[((size_t)b * MM + m) * DD + j];
    if (j >= 6) t_xs[m][j - 6] = v;
    else if (j == 2) t_cx[m] = v;
    else if (j == 3) t_cy[m] = v;
    else if (j == 4) t_th[m] = v;
  }
  // stage the 32 pred x-rows
  for (int idx = tid; idx < 32 * KK; idx += 256) {
    int ni = idx / KK, k = idx - ni * KK;
    px_s[ni][k] = preds[((size_t)b * NN + (n0 + ni)) * DD + 6 + k];
  }
  // stage pred cx,cy,th for the 32 rows
  if (tid < 96) {
    int ni = tid / 3, c = tid - ni * 3;
    pc_s[ni][c] = preds[((size_t)b * NN + (n0 + ni)) * DD + 2 + c];
  }
  // focal-cost class diffs (32 rows x 2 labels)
  if (tid >= 128 && tid < 192) {
    int q = tid - 128;
    int ni = q >> 1, c = q & 1;
    float lg = preds[((size_t)b * NN + (n0 + ni)) * DD + c];
    float pp = 1.0f / (1.0f + expf(-lg));
    float neg = -logf(1.0f - pp + EPSF) * 0.75f * (pp * pp);
    float pos = -logf(pp + EPSF) * 0.25f * ((1.0f - pp) * (1.0f - pp));
    cls[((size_t)b * NN + (n0 + ni)) * 2 + c] = pos - neg;
  }
  __syncthreads();
  // validity mask as 1.0/0.0 (multiplicative; fma-folds abs+mask+add)
  for (int idx = tid; idx < MM * KK; idx += 256) {
    int m = idx / KK, k = idx - m * KK;
    float t = t_xs[m][k];
    am_s[m][k] = (t >= 0.0f && t < imgw) ? 1.0f : 0.0f;
  }
  __syncthreads();
  if (tid < MM) {
    float V = 0.f;
    for (int k = 0; k < KK; ++k) V += am_s[tid][k];   // exact (<=72)
    t_len[tid] = (V > 0.f) ? V : 1.0f;
    v30[tid] = 30.0f * V;              // 2*IOU_LEN * valid-count (exact)
  }
  __syncthreads();

  const int m = tid >> 3;        // 0..31
  const int ni = tid & 7;        // 0..7

  float sad0 = 0.f, sad1 = 0.f, sad2 = 0.f, sad3 = 0.f;
  const float4* trow = reinterpret_cast<const float4*>(&t_xs[m][0]);
  const float4* arow = reinterpret_cast<const float4*>(&am_s[m][0]);
  const float4* p0 = reinterpret_cast<const float4*>(&px_s[ni][0]);
  const float4* p1 = reinterpret_cast<const float4*>(&px_s[ni + 8][0]);
  const float4* p2 = reinterpret_cast<const float4*>(&px_s[ni + 16][0]);
  const float4* p3 = reinterpret_cast<const float4*>(&px_s[ni + 24][0]);
#define STEP(T, A, Q, S) S = fmaf(fabsf((T) - (Q)), (A), S)
#pragma unroll
  for (int q = 0; q < KK / 4; ++q) {
    float4 t4 = trow[q], a4 = arow[q];
    float4 q0 = p0[q], q1 = p1[q], q2 = p2[q], q3 = p3[q];
    STEP(t4.x, a4.x, q0.x, sad0); STEP(t4.y, a4.y, q0.y, sad0);
    STEP(t4.z, a4.z, q0.z, sad0); STEP(t4.w, a4.w, q0.w, sad0);
    STEP(t4.x, a4.x, q1.x, sad1); STEP(t4.y, a4.y, q1.y, sad1);
    STEP(t4.z, a4.z, q1.z, sad1); STEP(t4.w, a4.w, q1.w, sad1);
    STEP(t4.x, a4.x, q2.x, sad2); STEP(t4.y, a4.y, q2.y, sad2);
    STEP(t4.z, a4.z, q2.z, sad2); STEP(t4.w, a4.w, q2.w, sad2);
    STEP(t4.x, a4.x, q3.x, sad3); STEP(t4.y, a4.y, q3.y, sad3);
    STEP(t4.z, a4.z, q3.z, sad3); STEP(t4.w, a4.w, q3.w, sad3);
  }
#undef STEP

  float md = 0.f, mxy = 0.f, mth = 0.f;
#pragma unroll
  for (int j = 0; j < 4; ++j) {
    int nrow = ni + 8 * j;
    float sad = (j == 0) ? sad0 : (j == 1) ? sad1 : (j == 2) ? sad2 : sad3;
    float dval = sad / t_len[m];
    float dx = pc_s[nrow][0] - t_cx[m], dy = pc_s[nrow][1] - t_cy[m];
    float xyv = sqrtf(dx * dx + dy * dy);
    float thv = fabsf(pc_s[nrow][2] - t_th[m]);
    // sum(ovr) = 30V - sad ; sum(union) = 30V + sad  (algebraic identity)
    float iv = (v30[m] - sad) / ((v30[m] + sad) + 1e-9f);
    pair4[((size_t)(b * MM + m)) * NN + n0 + nrow] =
        make_float4(dval, xyv, thv, iv);
    md = fmaxf(md, dval); mxy = fmaxf(mxy, xyv); mth = fmaxf(mth, thv);
  }

  // block max -> plain store to part[block][3] (NO atomics: round-5 lesson)
  for (int off = 32; off; off >>= 1) {
    md = fmaxf(md, __shfl_down(md, off));
    mxy = fmaxf(mxy, __shfl_down(mxy, off));
    mth = fmaxf(mth, __shfl_down(mth, off));
  }
  if ((tid & 63) == 0) {
    int w = tid >> 6;
    redv[w][0] = md; redv[w][1] = mxy; redv[w][2] = mth;
  }
  __syncthreads();
  if (tid == 0) {
    float a0 = fmaxf(fmaxf(redv[0][0], redv[1][0]), fmaxf(redv[2][0], redv[3][0]));
    float a1 = fmaxf(fmaxf(redv[0][1], redv[1][1]), fmaxf(redv[2][1], redv[3][1]));
    float a2 = fmaxf(fmaxf(redv[0][2], redv[1][2]), fmaxf(redv[2][2], redv[3][2]));
    part[(size_t)blockIdx.x * 3 + 0] = a0;
    part[(size_t)blockIdx.x * 3 + 1] = a1;
    part[(size_t)blockIdx.x * 3 + 2] = a2;
  }
}

// ---------- pass C: inline maxima reduce + fused cost + per-(b,m) top-4 -----
// one block (1024 threads = 16 waves) per (b,m); thread t owns n = 4t..4t+3
__global__ __launch_bounds__(1024) void k_assign(
    const float4* __restrict__ pair4, const float* __restrict__ cls,
    const float* __restrict__ tgts, const float* __restrict__ part,
    float* __restrict__ maxima, const void* __restrict__ masks,
    const int* __restrict__ flag, unsigned* __restrict__ mmask) {
  const int b = blockIdx.x >> 5;
  const int m = blockIdx.x & 31;
  if (!getmask(masks, *flag, b * MM + m)) return;   // block-uniform exit

  const int tid = threadIdx.x;
  __shared__ float wred[6];
  __shared__ float bcast[3];

  // reduce part[b*128 .. +127][3] -> batch maxima (replaces k_red launch)
  if (tid < 384) {
    int g = tid >> 7;              // metric 0..2
    int e = tid & 127;
    float v = part[((size_t)(b * 128 + e)) * 3 + g];
    for (int off = 32; off; off >>= 1) v = fmaxf(v, __shfl_down(v, off));
    if ((tid & 63) == 0) wred[tid >> 6] = v;
  }
  __syncthreads();
  if (tid == 0) {
    float a0 = fmaxf(wred[0], wred[1]);
    float a1 = fmaxf(wred[2], wred[3]);
    float a2 = fmaxf(wred[4], wred[5]);
    bcast[0] = a0; bcast[1] = a1; bcast[2] = a2;
    // benign same-value store (all unmasked blocks of batch b write identical values)
    maxima[b * 3 + 0] = a0; maxima[b * 3 + 1] = a1; maxima[b * 3 + 2] = a2;
  }
  __syncthreads();

  const float maxd = fmaxf(bcast[0], 1e-6f);
  const float maxxy = fmaxf(bcast[1], 1e-6f);
  const float maxth = fmaxf(bcast[2], 1e-6f);
  const int label = (int)tgts[((size_t)b * MM + m) * DD + 1];

  const int n0 = tid << 2;
  const float4* pp = pair4 + ((size_t)(b * MM + m)) * NN + n0;
  float4 q0 = pp[0], q1 = pp[1], q2 = pp[2], q3 = pp[3];
  const float4* cbase = reinterpret_cast<const float4*>(cls + ((size_t)b * NN + n0) * 2);
  float4 c0 = cbase[0], c1 = cbase[1];

  float de[4] = {q0.x, q1.x, q2.x, q3.x};
  float xe[4] = {q0.y, q1.y, q2.y, q3.y};
  float te[4] = {q0.z, q1.z, q2.z, q3.z};
  float ie[4] = {q0.w, q1.w, q2.w, q3.w};
  float clv[4] = {label ? c0.y : c0.x, label ? c0.w : c0.z,
                  label ? c1.y : c1.x, label ? c1.w : c1.z};

  float cc[4]; int ci[4]; float vv[4];
#pragma unroll
  for (int e = 0; e < 4; ++e) {
    float ds = (1.0f - de[e] / maxd) + 0.01f;
    float xs = (1.0f - xe[e] / maxxy) + 0.01f;
    float ts = (1.0f - te[e] / maxth) + 0.01f;
    float r = (ds * xs) * ts;
    cc[e] = -(r * r) * 3.0f + clv[e] * 1.0f;
    ci[e] = n0 + e;
    vv[e] = fmaxf(ie[e], 0.0f);
  }

  __shared__ float ls_c[64];  __shared__ int ls_ci[64];
  __shared__ float ls_v[64];  __shared__ int ls_vi[64];

  const int wid = tid >> 6, lane = tid & 63;
  unsigned usedC = 0, usedV = 0;
  float wcv[4]; int wci[4]; float wvv[4]; int wvi[4];

#pragma unroll
  for (int r = 0; r < 4; ++r) {
    // ---- cost: extract wave min by (c asc, idx asc) ----
    float bv = 3e38f; int bi = 0x7fffffff; int be = -1;
#pragma unroll
    for (int e = 0; e < 4; ++e)
      if (!((usedC >> e) & 1) && (cc[e] < bv || (cc[e] == bv && ci[e] < bi))) {
        bv = cc[e]; bi = ci[e]; be = e;
      }
    float v = bv; int i = bi;
#pragma unroll
    for (int off = 32; off; off >>= 1) {
      float ov = __shfl_xor(v, off); int oi = __shfl_xor(i, off);
      if (ov < v || (ov == v && oi < i)) { v = ov; i = oi; }
    }
    if (be >= 0 && i == bi) usedC |= 1u << be;   // unique n -> unique winner
    wcv[r] = v; wci[r] = i;

    // ---- iou: extract wave max by (v desc, idx asc) ----
    float bw = -1.0f; int bj = 0x7fffffff; int bf = -1;
#pragma unroll
    for (int e = 0; e < 4; ++e)
      if (!((usedV >> e) & 1) && (vv[e] > bw || (vv[e] == bw && ci[e] < bj))) {
        bw = vv[e]; bj = ci[e]; bf = e;
      }
    float w = bw; int j = bj;
#pragma unroll
    for (int off = 32; off; off >>= 1) {
      float ow = __shfl_xor(w, off); int oj = __shfl_xor(j, off);
      if (ow > w || (ow == w && oj < j)) { w = ow; j = oj; }
    }
    if (bf >= 0 && j == bj) usedV |= 1u << bf;
    wvv[r] = w; wvi[r] = j;
  }

  if (lane == 0) {
#pragma unroll
    for (int r = 0; r < 4; ++r) {
      ls_c[wid * 4 + r] = wcv[r]; ls_ci[wid * 4 + r] = wci[r];
      ls_v[wid * 4 + r] = wvv[r]; ls_vi[wid * 4 + r] = wvi[r];
    }
  }
  __syncthreads();

  if (tid < 64) {
    float c = ls_c[tid]; int i = ls_ci[tid];
    float w = ls_v[tid]; int j = ls_vi[tid];
    int gidx[4]; float gsum = 0.0f;
#pragma unroll
    for (int r = 0; r < 4; ++r) {
      float v = c; int vi = i;
#pragma unroll
      for (int off = 32; off; off >>= 1) {
        float ov = __shfl_xor(v, off); int oi = __shfl_xor(vi, off);
        if (ov < v || (ov == v && oi < vi)) { v = ov; vi = oi; }
      }
      if (i == vi) c = 3e38f;                    // consume winner
      gidx[r] = vi;

      float u = w; int ui = j;
#pragma unroll
      for (int off = 32; off; off >>= 1) {
        float ou = __shfl_xor(u, off); int oi = __shfl_xor(ui, off);
        if (ou > u || (ou == u && oi < ui)) { u = ou; ui = oi; }
      }
      if (j == ui) w = -1.0f;
      gsum += u;
    }
    if (tid == 0) {
      int k = (int)gsum;                         // trunc == floor (gsum >= 0)
      if (k < 1) k = 1;
      if (k > 4) k = 4;
      for (int s = 0; s < k; ++s)
        atomicOr(&mmask[(size_t)b * NN + gidx[s]], 1u << m);
    }
  }
}

// ---------- pass D: conflict resolution + outputs ---------------------------
__global__ __launch_bounds__(256) void k_final(
    const unsigned* __restrict__ mmask, const float4* __restrict__ pair4,
    const float* __restrict__ cls, const float* __restrict__ tgts,
    const float* __restrict__ maxima, int* __restrict__ out) {
  int idx = blockIdx.x * 256 + threadIdx.x;   // over B*N
  if (idx >= BB * NN) return;
  int b = idx >> 12;
  int n = idx & (NN - 1);
  unsigned mm = mmask[idx];
  int a, t;
  int pc = __popc(mm);
  if (pc == 0) {
    a = 0; t = -1;
  } else if (pc == 1) {
    a = 1; t = __ffs(mm) - 1;
  } else {
    a = 1;
    float maxd = fmaxf(maxima[b * 3 + 0], 1e-6f);
    float maxxy = fmaxf(maxima[b * 3 + 1], 1e-6f);
    float maxth = fmaxf(maxima[b * 3 + 2], 1e-6f);
    float best = 3e38f;
    int bi = -1;
    unsigned r0 = mm;
    while (r0) {
      int m = __ffs(r0) - 1;
      r0 &= r0 - 1;
      float4 q = pair4[((size_t)(b * MM + m)) * NN + n];
      int label = (int)tgts[((size_t)b * MM + m) * DD + 1];
      float ds = (1.0f - q.x / maxd) + 0.01f;
      float xs = (1.0f - q.y / maxxy) + 0.01f;
      float ts = (1.0f - q.z / maxth) + 0.01f;
      float r = (ds * xs) * ts;
      float c = -(r * r) * 3.0f + cls[((size_t)b * NN + n) * 2 + label] * 1.0f;
      if (c < best) { best = c; bi = m; }   // strict < -> lowest m wins ties
    }
    t = bi;
  }
  out[idx] = a;
  out[BB * NN + idx] = t;
}

extern "C" void kernel_launch(void* const* d_in, const int* in_sizes, int n_in,
                              void* d_out, int out_size, void* d_ws, size_t ws_size,
                              hipStream_t stream) {
  const float* preds = (const float*)d_in[0];
  const float* tgts = (const float*)d_in[1];
  const void* masks = d_in[2];
  const int* imgw = (const int*)d_in[3];

  char* ws = (char*)d_ws;
  float4* pair4 = (float4*)ws;                                // B*M*N*16 = 16.8 MB
  char* p = ws + (size_t)BB * MM * NN * sizeof(float4);
  float* cls = (float*)p;                                     // B*N*2 floats
  p += (size_t)BB * NN * 2 * sizeof(float);
  float* part = (float*)p;                                    // 1024*3 floats
  p += (size_t)1024 * 3 * sizeof(float);
  float* maxima = (float*)p;                                  // B*3
  p += 256;
  unsigned* mmask = (unsigned*)p;                             // B*N
  p += (size_t)BB * NN * sizeof(unsigned);
  int* flag = (int*)p;

  k_pairs<<<dim3(BB * 128), dim3(256), 0, stream>>>(
      preds, tgts, imgw, (const unsigned char*)masks, pair4, cls, part, mmask, flag);
  k_assign<<<dim3(BB * MM), dim3(1024), 0, stream>>>(
      pair4, cls, tgts, part, maxima, masks, flag, mmask);
  k_final<<<dim3((BB * NN + 255) / 256), dim3(256), 0, stream>>>(
      mmask, pair4, cls, tgts, maxima, (int*)d_out);
}

// Round 8
// 44.022 us; speedup vs baseline: 3.5683x; 1.2485x over previous
//
#include <hip/hip_runtime.h>
#include <stdint.h>

#define BB 8
#define NN 4096
#define MM 32
#define KK 72
#define DD 78
#define PAD 76            // LDS row stride (floats): 76*4=304 B, 16B-aligned

static constexpr float EPSF = 1e-12f;

__device__ inline bool getmask(const void* masks, int flag, int i) {
  if (flag) return ((const unsigned char*)masks)[i] != 0;
  return ((const int*)masks)[i] != 0;
}

// orderable key: min over (cost asc, m asc) == reference argmin-first semantics
__device__ inline unsigned long long packkey(float c, int m) {
  unsigned u = __float_as_uint(c);
  unsigned k = ((int)u < 0) ? ~u : (u ^ 0x80000000u);
  return ((unsigned long long)k << 32) | (unsigned)m;
}

// ---------- pass A: 1024 blocks = 8 b x 128 chunks(32 n); 256 thr = 32 m x 8 ni
// each thread computes 4 pairs. Outputs: sadA (4B/pair), pc4, cls, part maxima,
// zeroed mmask, ~0 cmin, flag.
__global__ __launch_bounds__(256) void k_pairs(
    const float* __restrict__ preds, const float* __restrict__ tgts,
    const int* __restrict__ imgw_p, const unsigned char* __restrict__ masks_raw,
    float* __restrict__ sadA, float4* __restrict__ pc4, float* __restrict__ cls,
    float* __restrict__ part, unsigned* __restrict__ mmask,
    unsigned long long* __restrict__ cmin, int* __restrict__ flag) {
  __shared__ __align__(16) float t_xs[MM][PAD];
  __shared__ __align__(16) float am_s[MM][PAD];   // valid ? 1.0 : 0.0
  __shared__ __align__(16) float px_s[32][PAD];
  __shared__ float pc_s[32][4];                   // cx, cy, th
  __shared__ float t_cx[MM], t_cy[MM], t_th[MM], t_len[MM];
  __shared__ float redv[4][3];

  const int b = blockIdx.x >> 7;
  const int n0 = (blockIdx.x & 127) << 5;         // 32 n per block
  const int tid = threadIdx.x;
  const float imgw = (float)(*imgw_p);

  // zero this block's mmask/cmin slice (1024 blocks x 32 = B*N)
  if (tid < 32) {
    mmask[blockIdx.x * 32 + tid] = 0u;
    cmin[blockIdx.x * 32 + tid] = ~0ull;
  }
  // mask dtype detect: int32 masks have zero bytes at i%4!=0
  if (blockIdx.x == 0 && tid < 64) {
    int i = tid * 4;
    bool nz = false;
#pragma unroll
    for (int j = 1; j < 4; ++j)
      if (masks_raw[i + j] != 0) nz = true;
    unsigned long long bal = __ballot(nz);
    if (tid == 0) *flag = (bal != 0ull) ? 1 : 0;
  }

  // stage targets for this batch
  for (int idx = tid; idx < MM * DD; idx += 256) {
    int m = idx / DD, j = idx - m * DD;
    float v = tgts[((size_t)b * MM + m) * DD + j];
    if (j >= 6) t_xs[m][j - 6] = v;
    else if (j == 2) t_cx[m] = v;
    else if (j == 3) t_cy[m] = v;
    else if (j == 4) t_th[m] = v;
  }
  // stage the 32 pred x-rows
  for (int idx = tid; idx < 32 * KK; idx += 256) {
    int ni = idx / KK, k = idx - ni * KK;
    px_s[ni][k] = preds[((size_t)b * NN + (n0 + ni)) * DD + 6 + k];
  }
  // stage pred cx,cy,th for the 32 rows
  if (tid < 96) {
    int ni = tid / 3, c = tid - ni * 3;
    pc_s[ni][c] = preds[((size_t)b * NN + (n0 + ni)) * DD + 2 + c];
  }
  // focal-cost class diffs (32 rows x 2 labels)
  if (tid >= 128 && tid < 192) {
    int q = tid - 128;
    int ni = q >> 1, c = q & 1;
    float lg = preds[((size_t)b * NN + (n0 + ni)) * DD + c];
    float pp = 1.0f / (1.0f + expf(-lg));
    float neg = -logf(1.0f - pp + EPSF) * 0.75f * (pp * pp);
    float pos = -logf(pp + EPSF) * 0.25f * ((1.0f - pp) * (1.0f - pp));
    cls[((size_t)b * NN + (n0 + ni)) * 2 + c] = pos - neg;
  }
  __syncthreads();
  // export compact (cx,cy,th) table for k_assign
  if (tid < 32)
    pc4[(size_t)b * NN + n0 + tid] =
        make_float4(pc_s[tid][0], pc_s[tid][1], pc_s[tid][2], 0.0f);
  // validity mask as 1.0/0.0 (multiplicative; fma folds abs+mask+add)
  for (int idx = tid; idx < MM * KK; idx += 256) {
    int m = idx / KK, k = idx - m * KK;
    float t = t_xs[m][k];
    am_s[m][k] = (t >= 0.0f && t < imgw) ? 1.0f : 0.0f;
  }
  __syncthreads();
  if (tid < MM) {
    float V = 0.f;
    for (int k = 0; k < KK; ++k) V += am_s[tid][k];   // exact (<=72)
    t_len[tid] = (V > 0.f) ? V : 1.0f;
  }
  __syncthreads();

  const int m = tid >> 3;        // 0..31
  const int ni = tid & 7;        // 0..7

  float sad0 = 0.f, sad1 = 0.f, sad2 = 0.f, sad3 = 0.f;
  const float4* trow = reinterpret_cast<const float4*>(&t_xs[m][0]);
  const float4* arow = reinterpret_cast<const float4*>(&am_s[m][0]);
  const float4* p0 = reinterpret_cast<const float4*>(&px_s[ni][0]);
  const float4* p1 = reinterpret_cast<const float4*>(&px_s[ni + 8][0]);
  const float4* p2 = reinterpret_cast<const float4*>(&px_s[ni + 16][0]);
  const float4* p3 = reinterpret_cast<const float4*>(&px_s[ni + 24][0]);
#define STEP(T, A, Q, S) S = fmaf(fabsf((T) - (Q)), (A), S)
#pragma unroll
  for (int q = 0; q < KK / 4; ++q) {
    float4 t4 = trow[q], a4 = arow[q];
    float4 q0 = p0[q], q1 = p1[q], q2 = p2[q], q3 = p3[q];
    STEP(t4.x, a4.x, q0.x, sad0); STEP(t4.y, a4.y, q0.y, sad0);
    STEP(t4.z, a4.z, q0.z, sad0); STEP(t4.w, a4.w, q0.w, sad0);
    STEP(t4.x, a4.x, q1.x, sad1); STEP(t4.y, a4.y, q1.y, sad1);
    STEP(t4.z, a4.z, q1.z, sad1); STEP(t4.w, a4.w, q1.w, sad1);
    STEP(t4.x, a4.x, q2.x, sad2); STEP(t4.y, a4.y, q2.y, sad2);
    STEP(t4.z, a4.z, q2.z, sad2); STEP(t4.w, a4.w, q2.w, sad2);
    STEP(t4.x, a4.x, q3.x, sad3); STEP(t4.y, a4.y, q3.y, sad3);
    STEP(t4.z, a4.z, q3.z, sad3); STEP(t4.w, a4.w, q3.w, sad3);
  }
#undef STEP

  float md = 0.f, mxy = 0.f, mth = 0.f;
#pragma unroll
  for (int j = 0; j < 4; ++j) {
    int nrow = ni + 8 * j;
    float sad = (j == 0) ? sad0 : (j == 1) ? sad1 : (j == 2) ? sad2 : sad3;
    float dval = sad / t_len[m];                  // IEEE div: bitwise == k_assign
    float dx = pc_s[nrow][0] - t_cx[m], dy = pc_s[nrow][1] - t_cy[m];
    float xyv = sqrtf(fmaf(dx, dx, dy * dy));     // explicit fma: same in k_assign
    float thv = fabsf(pc_s[nrow][2] - t_th[m]);
    sadA[((size_t)(b * MM + m)) * NN + n0 + nrow] = sad;
    md = fmaxf(md, dval); mxy = fmaxf(mxy, xyv); mth = fmaxf(mth, thv);
  }

  // block max -> plain store to part[block][3] (NO atomics: round-5 lesson)
  for (int off = 32; off; off >>= 1) {
    md = fmaxf(md, __shfl_down(md, off));
    mxy = fmaxf(mxy, __shfl_down(mxy, off));
    mth = fmaxf(mth, __shfl_down(mth, off));
  }
  if ((tid & 63) == 0) {
    int w = tid >> 6;
    redv[w][0] = md; redv[w][1] = mxy; redv[w][2] = mth;
  }
  __syncthreads();
  if (tid == 0) {
    float a0 = fmaxf(fmaxf(redv[0][0], redv[1][0]), fmaxf(redv[2][0], redv[3][0]));
    float a1 = fmaxf(fmaxf(redv[0][1], redv[1][1]), fmaxf(redv[2][1], redv[3][1]));
    float a2 = fmaxf(fmaxf(redv[0][2], redv[1][2]), fmaxf(redv[2][2], redv[3][2]));
    part[(size_t)blockIdx.x * 3 + 0] = a0;
    part[(size_t)blockIdx.x * 3 + 1] = a1;
    part[(size_t)blockIdx.x * 3 + 2] = a2;
  }
}

// ---------- pass C: maxima reduce + recompute metrics + cost + top-4 --------
// one block (1024 threads = 16 waves) per (b,m); thread t owns n = 4t..4t+3
__global__ __launch_bounds__(1024) void k_assign(
    const float* __restrict__ sadA, const float4* __restrict__ pc4,
    const float* __restrict__ cls, const float* __restrict__ tgts,
    const int* __restrict__ imgw_p, const float* __restrict__ part,
    const void* __restrict__ masks, const int* __restrict__ flag,
    unsigned* __restrict__ mmask, unsigned long long* __restrict__ cmin) {
  const int b = blockIdx.x >> 5;
  const int m = blockIdx.x & 31;
  if (!getmask(masks, *flag, b * MM + m)) return;   // block-uniform exit

  const int tid = threadIdx.x;
  __shared__ float wred[6];
  __shared__ float bcast[3];
  __shared__ float scal[8];   // 0:cx 1:cy 2:th 3:len 4:v30

  // reduce part[b*128 .. +127][3] -> batch maxima (waves 0-5)
  if (tid < 384) {
    int g = tid >> 7;              // metric 0..2
    int e = tid & 127;
    float v = part[((size_t)(b * 128 + e)) * 3 + g];
    for (int off = 32; off; off >>= 1) v = fmaxf(v, __shfl_down(v, off));
    if ((tid & 63) == 0) wred[tid >> 6] = v;
  }
  // wave 14: valid-count V for target row m (same predicate as k_pairs)
  if (tid >= 896 && tid < 960) {
    int lane = tid - 896;
    const float* trow = tgts + ((size_t)(b * MM + m)) * DD;
    const float imgw = (float)(*imgw_p);
    float t0 = trow[6 + lane];
    int c = (t0 >= 0.0f && t0 < imgw) ? 1 : 0;
    if (lane < KK - 64) {
      float t1 = trow[6 + 64 + lane];
      c += (t1 >= 0.0f && t1 < imgw) ? 1 : 0;
    }
    for (int off = 32; off; off >>= 1) c += __shfl_down(c, off);
    if (lane == 0) {
      float V = (float)c;
      scal[3] = (V > 0.f) ? V : 1.0f;
      scal[4] = 30.0f * V;
    }
  }
  if (tid == 1023) {
    const float* trow = tgts + ((size_t)(b * MM + m)) * DD;
    scal[0] = trow[2]; scal[1] = trow[3]; scal[2] = trow[4];
  }
  __syncthreads();
  if (tid == 0) {
    bcast[0] = fmaxf(wred[0], wred[1]);
    bcast[1] = fmaxf(wred[2], wred[3]);
    bcast[2] = fmaxf(wred[4], wred[5]);
  }
  __syncthreads();

  const float maxd = fmaxf(bcast[0], 1e-6f);
  const float maxxy = fmaxf(bcast[1], 1e-6f);
  const float maxth = fmaxf(bcast[2], 1e-6f);
  const float tcx = scal[0], tcy = scal[1], tth = scal[2];
  const float len = scal[3], v30 = scal[4];
  const int label = (int)tgts[((size_t)b * MM + m) * DD + 1];

  const int n0 = tid << 2;
  float4 s4 = *reinterpret_cast<const float4*>(sadA + ((size_t)(b * MM + m)) * NN + n0);
  const float4* pcb = pc4 + (size_t)b * NN + n0;
  float4 q0 = pcb[0], q1 = pcb[1], q2 = pcb[2], q3 = pcb[3];
  const float4* cbase = reinterpret_cast<const float4*>(cls + ((size_t)b * NN + n0) * 2);
  float4 c0 = cbase[0], c1 = cbase[1];

  float se[4] = {s4.x, s4.y, s4.z, s4.w};
  float cxe[4] = {q0.x, q1.x, q2.x, q3.x};
  float cye[4] = {q0.y, q1.y, q2.y, q3.y};
  float the[4] = {q0.z, q1.z, q2.z, q3.z};
  float clv[4] = {label ? c0.y : c0.x, label ? c0.w : c0.z,
                  label ? c1.y : c1.x, label ? c1.w : c1.z};

  float cc[4]; int ci[4]; float vv[4];
#pragma unroll
  for (int e = 0; e < 4; ++e) {
    float sad = se[e];
    float dval = sad / len;                       // == k_pairs dval bitwise
    float dx = cxe[e] - tcx, dy = cye[e] - tcy;
    float xyv = sqrtf(fmaf(dx, dx, dy * dy));     // == k_pairs xyv bitwise
    float thv = fabsf(the[e] - tth);
    float iv = (v30 - sad) / ((v30 + sad) + 1e-9f);
    float ds = (1.0f - dval / maxd) + 0.01f;
    float xs = (1.0f - xyv / maxxy) + 0.01f;
    float ts = (1.0f - thv / maxth) + 0.01f;
    float r = (ds * xs) * ts;
    cc[e] = -(r * r) * 3.0f + clv[e] * 1.0f;
    ci[e] = n0 + e;
    vv[e] = fmaxf(iv, 0.0f);
  }

  __shared__ float ls_c[64];  __shared__ int ls_ci[64];
  __shared__ float ls_v[64];  __shared__ int ls_vi[64];

  const int wid = tid >> 6, lane = tid & 63;
  unsigned usedC = 0, usedV = 0;
  float wcv[4]; int wci[4]; float wvv[4]; int wvi[4];

#pragma unroll
  for (int r = 0; r < 4; ++r) {
    // ---- cost: extract wave min by (c asc, idx asc) ----
    float bv = 3e38f; int bi = 0x7fffffff; int be = -1;
#pragma unroll
    for (int e = 0; e < 4; ++e)
      if (!((usedC >> e) & 1) && (cc[e] < bv || (cc[e] == bv && ci[e] < bi))) {
        bv = cc[e]; bi = ci[e]; be = e;
      }
    float v = bv; int i = bi;
#pragma unroll
    for (int off = 32; off; off >>= 1) {
      float ov = __shfl_xor(v, off); int oi = __shfl_xor(i, off);
      if (ov < v || (ov == v && oi < i)) { v = ov; i = oi; }
    }
    if (be >= 0 && i == bi) usedC |= 1u << be;   // unique n -> unique winner
    wcv[r] = v; wci[r] = i;

    // ---- iou: extract wave max by (v desc, idx asc) ----
    float bw = -1.0f; int bj = 0x7fffffff; int bf = -1;
#pragma unroll
    for (int e = 0; e < 4; ++e)
      if (!((usedV >> e) & 1) && (vv[e] > bw || (vv[e] == bw && ci[e] < bj))) {
        bw = vv[e]; bj = ci[e]; bf = e;
      }
    float w = bw; int j = bj;
#pragma unroll
    for (int off = 32; off; off >>= 1) {
      float ow = __shfl_xor(w, off); int oj = __shfl_xor(j, off);
      if (ow > w || (ow == w && oj < j)) { w = ow; j = oj; }
    }
    if (bf >= 0 && j == bj) usedV |= 1u << bf;
    wvv[r] = w; wvi[r] = j;
  }

  if (lane == 0) {
#pragma unroll
    for (int r = 0; r < 4; ++r) {
      ls_c[wid * 4 + r] = wcv[r]; ls_ci[wid * 4 + r] = wci[r];
      ls_v[wid * 4 + r] = wvv[r]; ls_vi[wid * 4 + r] = wvi[r];
    }
  }
  __syncthreads();

  if (tid < 64) {
    float c = ls_c[tid]; int i = ls_ci[tid];
    float w = ls_v[tid]; int j = ls_vi[tid];
    int gidx[4]; float gcst[4]; float gsum = 0.0f;
#pragma unroll
    for (int r = 0; r < 4; ++r) {
      float v = c; int vi = i;
#pragma unroll
      for (int off = 32; off; off >>= 1) {
        float ov = __shfl_xor(v, off); int oi = __shfl_xor(vi, off);
        if (ov < v || (ov == v && oi < vi)) { v = ov; vi = oi; }
      }
      if (i == vi) c = 3e38f;                    // consume winner
      gidx[r] = vi; gcst[r] = v;

      float u = w; int ui = j;
#pragma unroll
      for (int off = 32; off; off >>= 1) {
        float ou = __shfl_xor(u, off); int oi = __shfl_xor(ui, off);
        if (ou > u || (ou == u && oi < ui)) { u = ou; ui = oi; }
      }
      if (j == ui) w = -1.0f;
      gsum += u;
    }
    if (tid == 0) {
      int k = (int)gsum;                         // trunc == floor (gsum >= 0)
      if (k < 1) k = 1;
      if (k > 4) k = 4;
      for (int s = 0; s < k; ++s) {
        atomicOr(&mmask[(size_t)b * NN + gidx[s]], 1u << m);
        atomicMin(&cmin[(size_t)b * NN + gidx[s]], packkey(gcst[s], m));
      }
    }
  }
}

// ---------- pass D: trivial finalize ----------------------------------------
__global__ __launch_bounds__(256) void k_final(
    const unsigned* __restrict__ mmask,
    const unsigned long long* __restrict__ cmin, int* __restrict__ out) {
  int idx = blockIdx.x * 256 + threadIdx.x;   // over B*N
  if (idx >= BB * NN) return;
  unsigned mm = mmask[idx];
  int pc = __popc(mm);
  int t = pc ? (int)(unsigned)(cmin[idx] & 0xFFFFFFFFull) : -1;
  out[idx] = pc ? 1 : 0;
  out[BB * NN + idx] = t;
}

extern "C" void kernel_launch(void* const* d_in, const int* in_sizes, int n_in,
                              void* d_out, int out_size, void* d_ws, size_t ws_size,
                              hipStream_t stream) {
  const float* preds = (const float*)d_in[0];
  const float* tgts = (const float*)d_in[1];
  const void* masks = d_in[2];
  const int* imgw = (const int*)d_in[3];

  char* ws = (char*)d_ws;
  float* sadA = (float*)ws;                                   // B*M*N*4 = 4 MiB
  char* p = ws + (size_t)BB * MM * NN * sizeof(float);
  float4* pc4 = (float4*)p;                                   // B*N*16 = 512 KB
  p += (size_t)BB * NN * sizeof(float4);
  float* cls = (float*)p;                                     // B*N*2 floats
  p += (size_t)BB * NN * 2 * sizeof(float);
  float* part = (float*)p;                                    // 1024*3 floats
  p += (size_t)1024 * 3 * sizeof(float);
  unsigned* mmask = (unsigned*)p;                             // B*N
  p += (size_t)BB * NN * sizeof(unsigned);
  unsigned long long* cmin = (unsigned long long*)p;          // B*N * 8B
  p += (size_t)BB * NN * sizeof(unsigned long long);
  int* flag = (int*)p;

  k_pairs<<<dim3(BB * 128), dim3(256), 0, stream>>>(
      preds, tgts, imgw, (const unsigned char*)masks,
      sadA, pc4, cls, part, mmask, cmin, flag);
  k_assign<<<dim3(BB * MM), dim3(1024), 0, stream>>>(
      sadA, pc4, cls, tgts, imgw, part, masks, flag, mmask, cmin);
  k_final<<<dim3((BB * NN + 255) / 256), dim3(256), 0, stream>>>(
      mmask, cmin, (int*)d_out);
}